// Round 3
// baseline (406.499 us; speedup 1.0000x reference)
//
#include <hip/hip_runtime.h>

#define B_ 32
#define C_ 256
#define N_ 1024
#define D_ 64

// ---------------------------------------------------------------------------
// Kernel 1: Q,K projection, fp32, BIT-EXACT np.einsum emulation:
//   per element: acc=0; for c ascending: acc = fmaf(W[r][c], x[c][n], acc);
//   then one rounded add of bias. Stored qk[(b*128 + r)*N + n], r<64=q, r>=64=k.
// ---------------------------------------------------------------------------
__global__ __launch_bounds__(256) void qk32_kernel(
    const float* __restrict__ x,
    const float* __restrict__ wq, const float* __restrict__ bq,
    const float* __restrict__ wk, const float* __restrict__ bk,
    float* __restrict__ qk)
{
    const int nt = blockIdx.x;   // 0..3
    const int rt = blockIdx.y;   // 0..7
    const int b  = blockIdx.z;
    const int r0 = rt * 16;
    const int n  = nt * 256 + threadIdx.x;

    const float* wsrc = (r0 < 64) ? (wq + (size_t)r0 * C_) : (wk + (size_t)(r0 - 64) * C_);
    const float* bsrc = (r0 < 64) ? (bq + r0) : (bk + (r0 - 64));

    __shared__ __align__(16) float Wl[16][256];
    for (int i = threadIdx.x; i < 16 * 64; i += 256) {
        const int r = i >> 6; const int c4 = (i & 63) * 4;
        *(float4*)&Wl[r][c4] = *(const float4*)&wsrc[(size_t)r * C_ + c4];
    }
    __syncthreads();

    float acc[16];
    #pragma unroll
    for (int r = 0; r < 16; ++r) acc[r] = 0.f;

    const float* xb = x + (size_t)b * C_ * N_ + n;
    for (int c = 0; c < C_; ++c) {
        const float xv = xb[(size_t)c * N_];
        #pragma unroll
        for (int r = 0; r < 16; ++r) acc[r] = fmaf(Wl[r][c], xv, acc[r]);
    }

    #pragma unroll
    for (int r = 0; r < 16; ++r)
        qk[((size_t)b * 128 + r0 + r) * N_ + n] = acc[r] + bsrc[r];
}

// ---------------------------------------------------------------------------
// Kernel 2: V projection (fp32 tiled), V^T stored as (b, n, e) -> vt.
// Continuous path — only needs 2% accuracy; tiled fast version.
// ---------------------------------------------------------------------------
__global__ __launch_bounds__(256) void v_kernel(
    const float* __restrict__ x,
    const float* __restrict__ wv, const float* __restrict__ bv,
    float* __restrict__ vt)
{
    const int nt = blockIdx.x;   // 0..15
    const int rt = blockIdx.y;   // 0..3
    const int b  = blockIdx.z;
    const int n0 = nt * 64;

    const float* wsrc = wv + (size_t)rt * 64 * C_;
    const float* bsrc = bv + rt * 64;

    __shared__ __align__(16) float Wl[64][68];
    __shared__ __align__(16) float Xl[64][68];

    const int t  = threadIdx.x;
    const int tx = t & 15;
    const int ty = t >> 4;

    float acc[4][4];
    #pragma unroll
    for (int i = 0; i < 4; ++i)
        #pragma unroll
        for (int j = 0; j < 4; ++j) acc[i][j] = 0.f;

    const float* xb = x + (size_t)b * C_ * N_;

    for (int c0 = 0; c0 < C_; c0 += 64) {
        __syncthreads();
        #pragma unroll
        for (int p = 0; p < 4; ++p) {
            const int rl = (t >> 4) + p * 16;
            const int cl = (t & 15) * 4;
            *(float4*)&Wl[rl][cl] = *(const float4*)&wsrc[(size_t)rl * C_ + c0 + cl];
            *(float4*)&Xl[rl][cl] = *(const float4*)&xb[(size_t)(c0 + rl) * N_ + n0 + cl];
        }
        __syncthreads();

        #pragma unroll 8
        for (int kk = 0; kk < 64; ++kk) {
            const float4 bf = *(const float4*)&Xl[kk][tx * 4];
            const float a0 = Wl[ty*4+0][kk];
            const float a1 = Wl[ty*4+1][kk];
            const float a2 = Wl[ty*4+2][kk];
            const float a3 = Wl[ty*4+3][kk];
            acc[0][0] += a0*bf.x; acc[0][1] += a0*bf.y; acc[0][2] += a0*bf.z; acc[0][3] += a0*bf.w;
            acc[1][0] += a1*bf.x; acc[1][1] += a1*bf.y; acc[1][2] += a1*bf.z; acc[1][3] += a1*bf.w;
            acc[2][0] += a2*bf.x; acc[2][1] += a2*bf.y; acc[2][2] += a2*bf.z; acc[2][3] += a2*bf.w;
            acc[3][0] += a3*bf.x; acc[3][1] += a3*bf.y; acc[3][2] += a3*bf.z; acc[3][3] += a3*bf.w;
        }
    }

    const int col0 = n0 + tx * 4;
    const float bi0 = bsrc[ty*4+0], bi1 = bsrc[ty*4+1], bi2 = bsrc[ty*4+2], bi3 = bsrc[ty*4+3];
    const int e0 = rt * 64 + ty * 4;
    #pragma unroll
    for (int j = 0; j < 4; ++j) {
        float4 v; v.x = acc[0][j]+bi0; v.y = acc[1][j]+bi1; v.z = acc[2][j]+bi2; v.w = acc[3][j]+bi3;
        *(float4*)&vt[((size_t)b * N_ + col0 + j) * C_ + e0] = v;
    }
}

// ---------------------------------------------------------------------------
// Kernel 3: fp32 sim (bit-exact fmaf chain, d ascending) + top-8 + softmax +
//           fp32 V gather + residual. Block = 8 rows x 4 waves.
// ---------------------------------------------------------------------------
__global__ __launch_bounds__(256) void attn_kernel(
    const float* __restrict__ x,
    const float* __restrict__ qk,
    const float* __restrict__ vt,
    const float* __restrict__ scale,
    float* __restrict__ out)
{
    const int b  = blockIdx.y;
    const int n0 = blockIdx.x * 8;
    const int t  = threadIdx.x;
    const int lane = t & 63;
    const int w  = t >> 6;

    __shared__ float q_lds[8][64];
    __shared__ float cand_v[4][8][8];
    __shared__ int   cand_m[4][8][8];
    __shared__ __align__(16) float out_tile[8][260];

    for (int idx = t; idx < 512; idx += 256) {
        const int r = idx >> 6, d = idx & 63;
        q_lds[r][d] = qk[((size_t)b * 128 + d) * N_ + n0 + r];
    }
    __syncthreads();

    const int m_base = w * 256 + lane * 4;

    float a0[8], a1[8], a2[8], a3[8];
    #pragma unroll
    for (int r = 0; r < 8; ++r) { a0[r]=0.f; a1[r]=0.f; a2[r]=0.f; a3[r]=0.f; }

    const float* kb = qk + ((size_t)b * 128 + 64) * N_;
    #pragma unroll 4
    for (int d = 0; d < D_; ++d) {
        const float4 kv = *(const float4*)&kb[(size_t)d * N_ + m_base];
        #pragma unroll
        for (int r = 0; r < 8; ++r) {
            const float qv = q_lds[r][d];
            a0[r] = fmaf(qv, kv.x, a0[r]);
            a1[r] = fmaf(qv, kv.y, a1[r]);
            a2[r] = fmaf(qv, kv.z, a2[r]);
            a3[r] = fmaf(qv, kv.w, a3[r]);
        }
    }

    // ---- stage 1: per-wave top-8 per row (fp32, index tie-break) ----
    #pragma unroll 1
    for (int r = 0; r < 8; ++r) {
        const int nrow = n0 + r;
        float t0 = a0[r] * 0.125f; if (m_base + 0 == nrow) t0 = -1.0e9f;
        float t1 = a1[r] * 0.125f; if (m_base + 1 == nrow) t1 = -1.0e9f;
        float t2 = a2[r] * 0.125f; if (m_base + 2 == nrow) t2 = -1.0e9f;
        float t3 = a3[r] * 0.125f; if (m_base + 3 == nrow) t3 = -1.0e9f;
        #pragma unroll 1
        for (int round = 0; round < 8; ++round) {
            float v = t0; int m = m_base;
            if (t1 > v) { v = t1; m = m_base + 1; }
            if (t2 > v) { v = t2; m = m_base + 2; }
            if (t3 > v) { v = t3; m = m_base + 3; }
            #pragma unroll
            for (int off = 32; off >= 1; off >>= 1) {
                const float v2 = __shfl_xor(v, off);
                const int   m2 = __shfl_xor(m, off);
                if (v2 > v || (v2 == v && m2 < m)) { v = v2; m = m2; }
            }
            if (lane == 0) { cand_v[w][r][round] = v; cand_m[w][r][round] = m; }
            if      (m == m_base + 0) t0 = -3.0e38f;
            else if (m == m_base + 1) t1 = -3.0e38f;
            else if (m == m_base + 2) t2 = -3.0e38f;
            else if (m == m_base + 3) t3 = -3.0e38f;
        }
    }
    __syncthreads();

    // ---- stage 2: merge 4x8 candidates per row, softmax + V gather ----
    const float* vtb = vt + (size_t)b * N_ * C_;
    #pragma unroll 1
    for (int rr = 0; rr < 2; ++rr) {
        const int r = w * 2 + rr;
        float v; int m;
        if (lane < 32) { v = cand_v[lane >> 3][r][lane & 7]; m = cand_m[lane >> 3][r][lane & 7]; }
        else           { v = -3.0e38f; m = 0x40000000; }
        float4 o = make_float4(0.f, 0.f, 0.f, 0.f);
        float S = 0.f, vmax = 0.f;
        #pragma unroll 1
        for (int round = 0; round < 8; ++round) {
            float bvv = v; int bm = m;
            #pragma unroll
            for (int off = 32; off >= 1; off >>= 1) {
                const float v2 = __shfl_xor(bvv, off);
                const int   m2 = __shfl_xor(bm, off);
                if (v2 > bvv || (v2 == bvv && m2 < bm)) { bvv = v2; bm = m2; }
            }
            if (round == 0) vmax = bvv;
            const float e = __expf(bvv - vmax);
            S += e;
            const float4 vv = *(const float4*)&vtb[(size_t)bm * C_ + lane * 4];
            o.x += e * vv.x; o.y += e * vv.y; o.z += e * vv.z; o.w += e * vv.w;
            if (m == bm) v = -3.0e38f;
        }
        const float inv = 1.f / S;
        o.x *= inv; o.y *= inv; o.z *= inv; o.w *= inv;
        *(float4*)&out_tile[r][lane * 4] = o;
    }
    __syncthreads();

    // ---- residual + (b, c, n) write ----
    const float sc = scale[0];
    const float* xb = x + (size_t)b * C_ * N_;
    float* ob = out + (size_t)b * C_ * N_;
    #pragma unroll
    for (int i = 0; i < 8; ++i) {
        const int cc = i * 32 + (t >> 3);
        const int nl = t & 7;
        const size_t gi = (size_t)cc * N_ + n0 + nl;
        ob[gi] = xb[gi] + sc * out_tile[nl][cc];
    }
}

extern "C" void kernel_launch(void* const* d_in, const int* in_sizes, int n_in,
                              void* d_out, int out_size, void* d_ws, size_t ws_size,
                              hipStream_t stream) {
    const float* x     = (const float*)d_in[0];
    const float* wq    = (const float*)d_in[1];
    const float* bq    = (const float*)d_in[2];
    const float* wk    = (const float*)d_in[3];
    const float* bk    = (const float*)d_in[4];
    const float* wv    = (const float*)d_in[5];
    const float* bv    = (const float*)d_in[6];
    const float* scale = (const float*)d_in[7];
    float* out = (float*)d_out;

    // workspace: qk (b,128,n) fp32 = 16.8 MB | vt (b,n,c) fp32 = 33.6 MB
    float* qk = (float*)d_ws;
    float* vt = qk + (size_t)B_ * 128 * N_;

    qk32_kernel<<<dim3(4, 8, B_), 256, 0, stream>>>(x, wq, bq, wk, bk, qk);
    v_kernel<<<dim3(16, 4, B_), 256, 0, stream>>>(x, wv, bv, vt);
    attn_kernel<<<dim3(N_ / 8, B_), 256, 0, stream>>>(x, qk, vt, scale, out);
}

// Round 4
// 298.430 us; speedup vs baseline: 1.3621x; 1.3621x over previous
//
#include <hip/hip_runtime.h>

#define B_ 32
#define C_ 256
#define N_ 1024
#define D_ 64

// key = (monotone(v) << 10) | (1023 - m): larger key <=> larger v, tie -> smaller m.
__device__ __forceinline__ unsigned long long pack_key(float v, int m) {
    const unsigned int bits = __float_as_uint(v);
    const unsigned int mono = (bits & 0x80000000u) ? ~bits : (bits | 0x80000000u);
    return ((unsigned long long)mono << 10) | (unsigned long long)(1023 - m);
}

// ---------------------------------------------------------------------------
// Kernel 1: Q,K projection, fp32, bit-exact np.einsum emulation (ascending-c
// fmaf chain + one rounded bias add). qk[(b*128+r)*N+n], r<64=q, r>=64=k.
// W transposed in LDS -> float4 broadcast reads; 2 n per thread.
// ---------------------------------------------------------------------------
__global__ __launch_bounds__(256) void qk32_kernel(
    const float* __restrict__ x,
    const float* __restrict__ wq, const float* __restrict__ bq,
    const float* __restrict__ wk, const float* __restrict__ bk,
    float* __restrict__ qk)
{
    const int nt = blockIdx.x;   // 0..1
    const int rt = blockIdx.y;   // 0..7
    const int b  = blockIdx.z;
    const int r0 = rt * 16;
    const int n  = nt * 512 + threadIdx.x;   // covers n and n+256

    const float* wsrc = (r0 < 64) ? (wq + (size_t)r0 * C_) : (wk + (size_t)(r0 - 64) * C_);
    const float* bsrc = (r0 < 64) ? (bq + r0) : (bk + (r0 - 64));

    __shared__ __align__(16) float Wt[256][16];   // [c][r]
    for (int i = threadIdx.x; i < 16 * 64; i += 256) {
        const int r = i & 15;
        const int c4 = (i >> 4) * 4;
        const float4 wv4 = *(const float4*)&wsrc[(size_t)r * C_ + c4];
        Wt[c4+0][r] = wv4.x; Wt[c4+1][r] = wv4.y; Wt[c4+2][r] = wv4.z; Wt[c4+3][r] = wv4.w;
    }
    __syncthreads();

    float accA[16], accB[16];
    #pragma unroll
    for (int r = 0; r < 16; ++r) { accA[r] = 0.f; accB[r] = 0.f; }

    const float* xa = x + (size_t)b * C_ * N_ + n;
    #pragma unroll 2
    for (int c = 0; c < C_; ++c) {
        const float xva = xa[(size_t)c * N_];
        const float xvb = xa[(size_t)c * N_ + 256];
        float wv[16];
        *(float4*)&wv[0]  = *(const float4*)&Wt[c][0];
        *(float4*)&wv[4]  = *(const float4*)&Wt[c][4];
        *(float4*)&wv[8]  = *(const float4*)&Wt[c][8];
        *(float4*)&wv[12] = *(const float4*)&Wt[c][12];
        #pragma unroll
        for (int r = 0; r < 16; ++r) {
            accA[r] = fmaf(wv[r], xva, accA[r]);
            accB[r] = fmaf(wv[r], xvb, accB[r]);
        }
    }

    #pragma unroll
    for (int r = 0; r < 16; ++r) {
        const float bb = bsrc[r];
        float* dst = qk + ((size_t)b * 128 + r0 + r) * N_ + n;
        dst[0]   = accA[r] + bb;
        dst[256] = accB[r] + bb;
    }
}

// ---------------------------------------------------------------------------
// Kernel 2: V projection (fp32 tiled, continuous path). V^T (b,n,e) -> vt.
// W transposed in LDS -> float4 broadcast reads.
// ---------------------------------------------------------------------------
__global__ __launch_bounds__(256) void v_kernel(
    const float* __restrict__ x,
    const float* __restrict__ wv, const float* __restrict__ bv,
    float* __restrict__ vt)
{
    const int nt = blockIdx.x;   // 0..15
    const int rt = blockIdx.y;   // 0..3
    const int b  = blockIdx.z;
    const int n0 = nt * 64;

    const float* wsrc = wv + (size_t)rt * 64 * C_;
    const float* bsrc = bv + rt * 64;

    __shared__ __align__(16) float Wt[64][68];   // [c][row], 272B rows (16B-aligned)
    __shared__ __align__(16) float Xl[64][68];

    const int t  = threadIdx.x;
    const int tx = t & 15;
    const int ty = t >> 4;

    float acc[4][4];
    #pragma unroll
    for (int i = 0; i < 4; ++i)
        #pragma unroll
        for (int j = 0; j < 4; ++j) acc[i][j] = 0.f;

    const float* xb = x + (size_t)b * C_ * N_;

    for (int c0 = 0; c0 < C_; c0 += 64) {
        __syncthreads();
        #pragma unroll
        for (int p = 0; p < 4; ++p) {
            const int rl = (t >> 4) + p * 16;
            const int cl = (t & 15) * 4;
            const float4 w4 = *(const float4*)&wsrc[(size_t)rl * C_ + c0 + cl];
            Wt[cl+0][rl] = w4.x; Wt[cl+1][rl] = w4.y; Wt[cl+2][rl] = w4.z; Wt[cl+3][rl] = w4.w;
            *(float4*)&Xl[rl][cl] = *(const float4*)&xb[(size_t)(c0 + rl) * N_ + n0 + cl];
        }
        __syncthreads();

        #pragma unroll 8
        for (int kk = 0; kk < 64; ++kk) {
            const float4 bf = *(const float4*)&Xl[kk][tx * 4];
            const float4 af = *(const float4*)&Wt[kk][ty * 4];
            acc[0][0] += af.x*bf.x; acc[0][1] += af.x*bf.y; acc[0][2] += af.x*bf.z; acc[0][3] += af.x*bf.w;
            acc[1][0] += af.y*bf.x; acc[1][1] += af.y*bf.y; acc[1][2] += af.y*bf.z; acc[1][3] += af.y*bf.w;
            acc[2][0] += af.z*bf.x; acc[2][1] += af.z*bf.y; acc[2][2] += af.z*bf.z; acc[2][3] += af.z*bf.w;
            acc[3][0] += af.w*bf.x; acc[3][1] += af.w*bf.y; acc[3][2] += af.w*bf.z; acc[3][3] += af.w*bf.w;
        }
    }

    const int col0 = n0 + tx * 4;
    const float bi0 = bsrc[ty*4+0], bi1 = bsrc[ty*4+1], bi2 = bsrc[ty*4+2], bi3 = bsrc[ty*4+3];
    const int e0 = rt * 64 + ty * 4;
    #pragma unroll
    for (int j = 0; j < 4; ++j) {
        float4 v; v.x = acc[0][j]+bi0; v.y = acc[1][j]+bi1; v.z = acc[2][j]+bi2; v.w = acc[3][j]+bi3;
        *(float4*)&vt[((size_t)b * N_ + col0 + j) * C_ + e0] = v;
    }
}

// ---------------------------------------------------------------------------
// Kernel 3: fp32 sim (bit-exact ascending-d fmaf chain, raw values — /8 is an
// exact scale so selection order is unchanged) + threshold-filtered exact
// top-8 + softmax + fp32 V gather + residual.
// Block = 8 rows x 4 waves; wave w owns m-slice [256w, 256w+256), 4 m/lane.
// Stage A: T = min of 8 group-of-8-lane maxes (provably <= V8 of slice),
//          compact values >= T as u64 keys into LDS (cap 32, exact fallback).
// Stage B: per row, 8 extraction rounds over <=128 keys (2/lane) with fused
//          softmax + V^T gather.
// ---------------------------------------------------------------------------
__global__ __launch_bounds__(256) void attn_kernel(
    const float* __restrict__ x,
    const float* __restrict__ qk,
    const float* __restrict__ vt,
    const float* __restrict__ scale,
    float* __restrict__ out)
{
    const int b  = blockIdx.y;
    const int n0 = blockIdx.x * 8;
    const int t  = threadIdx.x;
    const int lane = t & 63;
    const int w  = t >> 6;

    __shared__ __align__(16) float q_lds[8][64];
    __shared__ unsigned long long cand[8][4][32];
    __shared__ int ccnt[8][4];
    __shared__ __align__(16) float out_tile[8][260];

    for (int idx = t; idx < 512; idx += 256) {
        const int r = idx >> 6, d = idx & 63;
        q_lds[r][d] = qk[((size_t)b * 128 + d) * N_ + n0 + r];
    }
    __syncthreads();

    const int m_base = w * 256 + lane * 4;

    float a0[8], a1[8], a2[8], a3[8];
    #pragma unroll
    for (int r = 0; r < 8; ++r) { a0[r]=0.f; a1[r]=0.f; a2[r]=0.f; a3[r]=0.f; }

    const float* kb = qk + ((size_t)b * 128 + 64) * N_ + m_base;
    #pragma unroll 2
    for (int d0 = 0; d0 < D_; d0 += 4) {
        const float4 k0 = *(const float4*)&kb[(size_t)(d0+0) * N_];
        const float4 k1 = *(const float4*)&kb[(size_t)(d0+1) * N_];
        const float4 k2 = *(const float4*)&kb[(size_t)(d0+2) * N_];
        const float4 k3 = *(const float4*)&kb[(size_t)(d0+3) * N_];
        #pragma unroll
        for (int r = 0; r < 8; ++r) {
            const float4 qf = *(const float4*)&q_lds[r][d0];
            a0[r] = fmaf(qf.x, k0.x, a0[r]); a0[r] = fmaf(qf.y, k1.x, a0[r]);
            a0[r] = fmaf(qf.z, k2.x, a0[r]); a0[r] = fmaf(qf.w, k3.x, a0[r]);
            a1[r] = fmaf(qf.x, k0.y, a1[r]); a1[r] = fmaf(qf.y, k1.y, a1[r]);
            a1[r] = fmaf(qf.z, k2.y, a1[r]); a1[r] = fmaf(qf.w, k3.y, a1[r]);
            a2[r] = fmaf(qf.x, k0.z, a2[r]); a2[r] = fmaf(qf.y, k1.z, a2[r]);
            a2[r] = fmaf(qf.z, k2.z, a2[r]); a2[r] = fmaf(qf.w, k3.z, a2[r]);
            a3[r] = fmaf(qf.x, k0.w, a3[r]); a3[r] = fmaf(qf.y, k1.w, a3[r]);
            a3[r] = fmaf(qf.z, k2.w, a3[r]); a3[r] = fmaf(qf.w, k3.w, a3[r]);
        }
    }

    // ---- stage A: threshold-filter + compaction (exact superset of top-8) ----
    const unsigned long long lt = (1ull << lane) - 1ull;   // lanes below (lane<64)
    #pragma unroll
    for (int r = 0; r < 8; ++r) {
        const int nrow = n0 + r;
        float t0 = a0[r], t1 = a1[r], t2 = a2[r], t3 = a3[r];
        const int dj = nrow - m_base;
        if      (dj == 0) t0 = -1.0e9f;
        else if (dj == 1) t1 = -1.0e9f;
        else if (dj == 2) t2 = -1.0e9f;
        else if (dj == 3) t3 = -1.0e9f;

        float lm = fmaxf(fmaxf(t0, t1), fmaxf(t2, t3));
        lm = fmaxf(lm, __shfl_xor(lm, 1));
        lm = fmaxf(lm, __shfl_xor(lm, 2));
        lm = fmaxf(lm, __shfl_xor(lm, 4));      // group-of-8 max
        float Th = lm;
        Th = fminf(Th, __shfl_xor(Th, 8));
        Th = fminf(Th, __shfl_xor(Th, 16));
        Th = fminf(Th, __shfl_xor(Th, 32));     // min of 8 group maxes <= V8

        int cnt = 0;
        {
            const bool p = (t0 >= Th);
            const unsigned long long msk = __ballot(p);
            const int pos = cnt + (int)__popcll(msk & lt);
            if (p && pos < 32) cand[r][w][pos] = pack_key(t0, m_base + 0);
            cnt += (int)__popcll(msk);
        }
        {
            const bool p = (t1 >= Th);
            const unsigned long long msk = __ballot(p);
            const int pos = cnt + (int)__popcll(msk & lt);
            if (p && pos < 32) cand[r][w][pos] = pack_key(t1, m_base + 1);
            cnt += (int)__popcll(msk);
        }
        {
            const bool p = (t2 >= Th);
            const unsigned long long msk = __ballot(p);
            const int pos = cnt + (int)__popcll(msk & lt);
            if (p && pos < 32) cand[r][w][pos] = pack_key(t2, m_base + 2);
            cnt += (int)__popcll(msk);
        }
        {
            const bool p = (t3 >= Th);
            const unsigned long long msk = __ballot(p);
            const int pos = cnt + (int)__popcll(msk & lt);
            if (p && pos < 32) cand[r][w][pos] = pack_key(t3, m_base + 3);
            cnt += (int)__popcll(msk);
        }

        if (cnt > 32) {   // exact fallback: slice top-8 via 8 extraction rounds
            unsigned long long K0 = pack_key(t0, m_base + 0);
            unsigned long long K1 = pack_key(t1, m_base + 1);
            unsigned long long K2 = pack_key(t2, m_base + 2);
            unsigned long long K3 = pack_key(t3, m_base + 3);
            #pragma unroll 1
            for (int round = 0; round < 8; ++round) {
                unsigned long long kl = K0 > K1 ? K0 : K1;
                kl = K2 > kl ? K2 : kl;
                kl = K3 > kl ? K3 : kl;
                #pragma unroll
                for (int off = 32; off >= 1; off >>= 1) {
                    const unsigned long long ks = __shfl_xor(kl, off);
                    if (ks > kl) kl = ks;
                }
                if (lane == 0) cand[r][w][round] = kl;
                if      (K0 == kl) K0 = 0ull;
                else if (K1 == kl) K1 = 0ull;
                else if (K2 == kl) K2 = 0ull;
                else if (K3 == kl) K3 = 0ull;
            }
            cnt = 8;
        }
        if (lane == 0) ccnt[r][w] = cnt;
    }
    __syncthreads();

    // ---- stage B: per-row exact top-8 of candidates + softmax + V gather ----
    const float* vtb = vt + (size_t)b * N_ * C_;
    #pragma unroll 1
    for (int rr = 0; rr < 2; ++rr) {
        const int r = w * 2 + rr;
        const int seg = lane >> 5;
        const int idx = lane & 31;
        unsigned long long k0 = (idx < ccnt[r][seg])     ? cand[r][seg][idx]     : 0ull;
        unsigned long long k1 = (idx < ccnt[r][seg + 2]) ? cand[r][seg + 2][idx] : 0ull;
        float4 o = make_float4(0.f, 0.f, 0.f, 0.f);
        float S = 0.f, vmax = 0.f;
        #pragma unroll 1
        for (int round = 0; round < 8; ++round) {
            unsigned long long km = k0 > k1 ? k0 : k1;
            #pragma unroll
            for (int off = 32; off >= 1; off >>= 1) {
                const unsigned long long ks = __shfl_xor(km, off);
                if (ks > km) km = ks;
            }
            const unsigned int mono = (unsigned int)(km >> 10);
            const unsigned int mm   = 1023u - ((unsigned int)km & 1023u);
            const unsigned int bits = (mono & 0x80000000u) ? (mono & 0x7FFFFFFFu) : ~mono;
            const float vraw = __uint_as_float(bits);
            if (round == 0) vmax = vraw;
            const float e = __expf((vraw - vmax) * 0.125f);
            S += e;
            const float4 vv = *(const float4*)&vtb[(size_t)mm * C_ + lane * 4];
            o.x += e * vv.x; o.y += e * vv.y; o.z += e * vv.z; o.w += e * vv.w;
            if (k0 == km) k0 = 0ull;
            if (k1 == km) k1 = 0ull;
        }
        const float inv = 1.f / S;
        *(float4*)&out_tile[r][lane * 4] = make_float4(o.x*inv, o.y*inv, o.z*inv, o.w*inv);
    }
    __syncthreads();

    // ---- residual + (b, c, n) write ----
    const float sc = scale[0];
    const float* xb = x + (size_t)b * C_ * N_;
    float* ob = out + (size_t)b * C_ * N_;
    #pragma unroll
    for (int i = 0; i < 8; ++i) {
        const int cc = i * 32 + (t >> 3);
        const int nl = t & 7;
        const size_t gi = (size_t)cc * N_ + n0 + nl;
        ob[gi] = xb[gi] + sc * out_tile[nl][cc];
    }
}

extern "C" void kernel_launch(void* const* d_in, const int* in_sizes, int n_in,
                              void* d_out, int out_size, void* d_ws, size_t ws_size,
                              hipStream_t stream) {
    const float* x     = (const float*)d_in[0];
    const float* wq    = (const float*)d_in[1];
    const float* bq    = (const float*)d_in[2];
    const float* wk    = (const float*)d_in[3];
    const float* bk    = (const float*)d_in[4];
    const float* wv    = (const float*)d_in[5];
    const float* bv    = (const float*)d_in[6];
    const float* scale = (const float*)d_in[7];
    float* out = (float*)d_out;

    float* qk = (float*)d_ws;                    // (b,128,n) fp32 = 16.8 MB
    float* vt = qk + (size_t)B_ * 128 * N_;      // (b,n,c)  fp32 = 33.6 MB

    qk32_kernel<<<dim3(2, 8, B_), 256, 0, stream>>>(x, wq, bq, wk, bk, qk);
    v_kernel<<<dim3(16, 4, B_), 256, 0, stream>>>(x, wv, bv, vt);
    attn_kernel<<<dim3(N_ / 8, B_), 256, 0, stream>>>(x, qk, vt, scale, out);
}

// Round 5
// 263.466 us; speedup vs baseline: 1.5429x; 1.1327x over previous
//
#include <hip/hip_runtime.h>

#define B_ 32
#define C_ 256
#define N_ 1024
#define D_ 64

// key = (monotone(v) << 10) | (1023 - m): larger key <=> larger v, tie -> smaller m.
__device__ __forceinline__ unsigned long long pack_key(float v, int m) {
    const unsigned int bits = __float_as_uint(v);
    const unsigned int mono = (bits & 0x80000000u) ? ~bits : (bits | 0x80000000u);
    return ((unsigned long long)mono << 10) | (unsigned long long)(1023 - m);
}

// ---------------------------------------------------------------------------
// Merged projection kernel. Grid: (80, B).
//   bx <  64: V projection tile (nt = bx&15, rt = bx>>4)   -> vt (b, n, e)
//   bx >= 64: Q,K projection (idx = bx-64: nt = idx&1, rt = idx>>1)
//             bit-exact np.einsum emulation (ascending-c fmaf chain + one
//             rounded bias add) -> qk[(b*128+r)*N + n], r<64=q, r>=64=k.
// Shared memory aliased between the two paths (34.8 KB).
// ---------------------------------------------------------------------------
__global__ __launch_bounds__(256) void proj_kernel(
    const float* __restrict__ x,
    const float* __restrict__ wq, const float* __restrict__ bq,
    const float* __restrict__ wk, const float* __restrict__ bk,
    const float* __restrict__ wv, const float* __restrict__ bv,
    float* __restrict__ qk, float* __restrict__ vt)
{
    const int bx = blockIdx.x;
    const int b  = blockIdx.y;
    const int t  = threadIdx.x;

    __shared__ __align__(16) float smem[2 * 64 * 68];   // 34816 B

    if (bx < 64) {
        // ---------------- V path: 64x64 tile, fp32 (continuous, 2% tol) ----
        const int nt = bx & 15;
        const int rt = bx >> 4;
        const int n0 = nt * 64;

        const float* wsrc = wv + (size_t)rt * 64 * C_;
        const float* bsrc = bv + rt * 64;

        float* Wt = smem;                 // [c][row] : [64][68]
        float* Xl = smem + 64 * 68;       // [c][n]   : [64][68]

        const int tx = t & 15;
        const int ty = t >> 4;

        float acc[4][4];
        #pragma unroll
        for (int i = 0; i < 4; ++i)
            #pragma unroll
            for (int j = 0; j < 4; ++j) acc[i][j] = 0.f;

        const float* xb = x + (size_t)b * C_ * N_;

        for (int c0 = 0; c0 < C_; c0 += 64) {
            __syncthreads();
            #pragma unroll
            for (int p = 0; p < 4; ++p) {
                const int rl = (t >> 4) + p * 16;
                const int cl = (t & 15) * 4;
                const float4 w4 = *(const float4*)&wsrc[(size_t)rl * C_ + c0 + cl];
                Wt[(cl+0)*68 + rl] = w4.x; Wt[(cl+1)*68 + rl] = w4.y;
                Wt[(cl+2)*68 + rl] = w4.z; Wt[(cl+3)*68 + rl] = w4.w;
                *(float4*)&Xl[rl*68 + cl] = *(const float4*)&xb[(size_t)(c0 + rl) * N_ + n0 + cl];
            }
            __syncthreads();

            #pragma unroll 8
            for (int kk = 0; kk < 64; ++kk) {
                const float4 bf = *(const float4*)&Xl[kk*68 + tx * 4];
                const float4 af = *(const float4*)&Wt[kk*68 + ty * 4];
                acc[0][0] += af.x*bf.x; acc[0][1] += af.x*bf.y; acc[0][2] += af.x*bf.z; acc[0][3] += af.x*bf.w;
                acc[1][0] += af.y*bf.x; acc[1][1] += af.y*bf.y; acc[1][2] += af.y*bf.z; acc[1][3] += af.y*bf.w;
                acc[2][0] += af.z*bf.x; acc[2][1] += af.z*bf.y; acc[2][2] += af.z*bf.z; acc[2][3] += af.z*bf.w;
                acc[3][0] += af.w*bf.x; acc[3][1] += af.w*bf.y; acc[3][2] += af.w*bf.z; acc[3][3] += af.w*bf.w;
            }
        }

        const int col0 = n0 + tx * 4;
        const float bi0 = bsrc[ty*4+0], bi1 = bsrc[ty*4+1], bi2 = bsrc[ty*4+2], bi3 = bsrc[ty*4+3];
        const int e0 = rt * 64 + ty * 4;
        #pragma unroll
        for (int j = 0; j < 4; ++j) {
            float4 v; v.x = acc[0][j]+bi0; v.y = acc[1][j]+bi1; v.z = acc[2][j]+bi2; v.w = acc[3][j]+bi3;
            *(float4*)&vt[((size_t)b * N_ + col0 + j) * C_ + e0] = v;
        }
    } else {
        // ---------------- Q,K path: bit-exact fmaf chain ----
        const int idx = bx - 64;          // 0..15
        const int nt = idx & 1;
        const int rt = idx >> 1;          // 0..7
        const int r0 = rt * 16;
        const int n  = nt * 512 + t;      // covers n and n+256

        const float* wsrc = (r0 < 64) ? (wq + (size_t)r0 * C_) : (wk + (size_t)(r0 - 64) * C_);
        const float* bsrc = (r0 < 64) ? (bq + r0) : (bk + (r0 - 64));

        float* Wt = smem;                 // [c][r] : [256][16]
        for (int i = t; i < 16 * 64; i += 256) {
            const int r  = i & 15;
            const int c4 = (i >> 4) * 4;
            const float4 wv4 = *(const float4*)&wsrc[(size_t)r * C_ + c4];
            Wt[(c4+0)*16 + r] = wv4.x; Wt[(c4+1)*16 + r] = wv4.y;
            Wt[(c4+2)*16 + r] = wv4.z; Wt[(c4+3)*16 + r] = wv4.w;
        }
        __syncthreads();

        float accA[16], accB[16];
        #pragma unroll
        for (int r = 0; r < 16; ++r) { accA[r] = 0.f; accB[r] = 0.f; }

        const float* xa = x + (size_t)b * C_ * N_ + n;
        #pragma unroll 2
        for (int c = 0; c < C_; ++c) {
            const float xva = xa[(size_t)c * N_];
            const float xvb = xa[(size_t)c * N_ + 256];
            float wvr[16];
            *(float4*)&wvr[0]  = *(const float4*)&Wt[c*16 + 0];
            *(float4*)&wvr[4]  = *(const float4*)&Wt[c*16 + 4];
            *(float4*)&wvr[8]  = *(const float4*)&Wt[c*16 + 8];
            *(float4*)&wvr[12] = *(const float4*)&Wt[c*16 + 12];
            #pragma unroll
            for (int r = 0; r < 16; ++r) {
                accA[r] = fmaf(wvr[r], xva, accA[r]);
                accB[r] = fmaf(wvr[r], xvb, accB[r]);
            }
        }

        #pragma unroll
        for (int r = 0; r < 16; ++r) {
            const float bb = bsrc[r];
            float* dst = qk + ((size_t)b * 128 + r0 + r) * N_ + n;
            dst[0]   = accA[r] + bb;
            dst[256] = accB[r] + bb;
        }
    }
}

// ---------------------------------------------------------------------------
// Attention kernel: fp32 sim (bit-exact ascending-d fmaf chain on raw values;
// /8 is an exact scale applied only inside exp) + threshold-filtered exact
// top-8 + softmax + fp32 V gather + residual.
// Block = 16 rows x 4 waves; wave w owns m-slice [256w, 256w+256), 4 m/lane.
// K loads register-double-buffered so L2 latency drains under the FMA block.
// ---------------------------------------------------------------------------
__global__ __launch_bounds__(256) void attn_kernel(
    const float* __restrict__ x,
    const float* __restrict__ qk,
    const float* __restrict__ vt,
    const float* __restrict__ scale,
    float* __restrict__ out)
{
    const int b  = blockIdx.y;
    const int n0 = blockIdx.x * 16;
    const int t  = threadIdx.x;
    const int lane = t & 63;
    const int w  = t >> 6;

    __shared__ __align__(16) float q_lds[16][64];           // 4 KB
    __shared__ unsigned long long cand[16][4][32];          // 16 KB
    __shared__ int ccnt[16][4];
    __shared__ __align__(16) float out_tile[16][260];       // 16.25 KB

    for (int idx = t; idx < 1024; idx += 256) {
        const int r = idx & 15, d = idx >> 4;
        q_lds[r][d] = qk[((size_t)b * 128 + d) * N_ + n0 + r];
    }
    __syncthreads();

    const int m_base = w * 256 + lane * 4;

    float a0[16], a1[16], a2[16], a3[16];
    #pragma unroll
    for (int r = 0; r < 16; ++r) { a0[r]=0.f; a1[r]=0.f; a2[r]=0.f; a3[r]=0.f; }

    const float* kb = qk + ((size_t)b * 128 + 64) * N_ + m_base;

    float4 kc0 = *(const float4*)&kb[0 * N_];
    float4 kc1 = *(const float4*)&kb[1 * N_];
    float4 kc2 = *(const float4*)&kb[2 * N_];
    float4 kc3 = *(const float4*)&kb[3 * N_];

    #pragma unroll 1
    for (int d0 = 0; d0 < D_; d0 += 4) {
        float4 kn0, kn1, kn2, kn3;
        if (d0 + 4 < D_) {
            kn0 = *(const float4*)&kb[(size_t)(d0+4) * N_];
            kn1 = *(const float4*)&kb[(size_t)(d0+5) * N_];
            kn2 = *(const float4*)&kb[(size_t)(d0+6) * N_];
            kn3 = *(const float4*)&kb[(size_t)(d0+7) * N_];
        }
        #pragma unroll
        for (int r = 0; r < 16; ++r) {
            const float4 qf = *(const float4*)&q_lds[r][d0];
            a0[r] = fmaf(qf.x, kc0.x, a0[r]); a0[r] = fmaf(qf.y, kc1.x, a0[r]);
            a0[r] = fmaf(qf.z, kc2.x, a0[r]); a0[r] = fmaf(qf.w, kc3.x, a0[r]);
            a1[r] = fmaf(qf.x, kc0.y, a1[r]); a1[r] = fmaf(qf.y, kc1.y, a1[r]);
            a1[r] = fmaf(qf.z, kc2.y, a1[r]); a1[r] = fmaf(qf.w, kc3.y, a1[r]);
            a2[r] = fmaf(qf.x, kc0.z, a2[r]); a2[r] = fmaf(qf.y, kc1.z, a2[r]);
            a2[r] = fmaf(qf.z, kc2.z, a2[r]); a2[r] = fmaf(qf.w, kc3.z, a2[r]);
            a3[r] = fmaf(qf.x, kc0.w, a3[r]); a3[r] = fmaf(qf.y, kc1.w, a3[r]);
            a3[r] = fmaf(qf.z, kc2.w, a3[r]); a3[r] = fmaf(qf.w, kc3.w, a3[r]);
        }
        if (d0 + 4 < D_) { kc0 = kn0; kc1 = kn1; kc2 = kn2; kc3 = kn3; }
    }

    // ---- stage A: threshold-filter + compaction (exact superset of top-8) ----
    const unsigned long long lt = (1ull << lane) - 1ull;
    #pragma unroll
    for (int r = 0; r < 16; ++r) {
        const int nrow = n0 + r;
        float t0 = a0[r], t1 = a1[r], t2 = a2[r], t3 = a3[r];
        const int dj = nrow - m_base;
        if      (dj == 0) t0 = -1.0e9f;
        else if (dj == 1) t1 = -1.0e9f;
        else if (dj == 2) t2 = -1.0e9f;
        else if (dj == 3) t3 = -1.0e9f;

        float lm = fmaxf(fmaxf(t0, t1), fmaxf(t2, t3));
        lm = fmaxf(lm, __shfl_xor(lm, 1));
        lm = fmaxf(lm, __shfl_xor(lm, 2));
        lm = fmaxf(lm, __shfl_xor(lm, 4));      // group-of-8 max
        float Th = lm;
        Th = fminf(Th, __shfl_xor(Th, 8));
        Th = fminf(Th, __shfl_xor(Th, 16));
        Th = fminf(Th, __shfl_xor(Th, 32));     // min of 8 group maxes <= V8

        int cnt = 0;
        {
            const bool p = (t0 >= Th);
            const unsigned long long msk = __ballot(p);
            const int pos = cnt + (int)__popcll(msk & lt);
            if (p && pos < 32) cand[r][w][pos] = pack_key(t0, m_base + 0);
            cnt += (int)__popcll(msk);
        }
        {
            const bool p = (t1 >= Th);
            const unsigned long long msk = __ballot(p);
            const int pos = cnt + (int)__popcll(msk & lt);
            if (p && pos < 32) cand[r][w][pos] = pack_key(t1, m_base + 1);
            cnt += (int)__popcll(msk);
        }
        {
            const bool p = (t2 >= Th);
            const unsigned long long msk = __ballot(p);
            const int pos = cnt + (int)__popcll(msk & lt);
            if (p && pos < 32) cand[r][w][pos] = pack_key(t2, m_base + 2);
            cnt += (int)__popcll(msk);
        }
        {
            const bool p = (t3 >= Th);
            const unsigned long long msk = __ballot(p);
            const int pos = cnt + (int)__popcll(msk & lt);
            if (p && pos < 32) cand[r][w][pos] = pack_key(t3, m_base + 3);
            cnt += (int)__popcll(msk);
        }

        if (cnt > 32) {   // exact fallback: slice top-8 via 8 extraction rounds
            unsigned long long K0 = pack_key(t0, m_base + 0);
            unsigned long long K1 = pack_key(t1, m_base + 1);
            unsigned long long K2 = pack_key(t2, m_base + 2);
            unsigned long long K3 = pack_key(t3, m_base + 3);
            #pragma unroll 1
            for (int round = 0; round < 8; ++round) {
                unsigned long long kl = K0 > K1 ? K0 : K1;
                kl = K2 > kl ? K2 : kl;
                kl = K3 > kl ? K3 : kl;
                #pragma unroll
                for (int off = 32; off >= 1; off >>= 1) {
                    const unsigned long long ks = __shfl_xor(kl, off);
                    if (ks > kl) kl = ks;
                }
                if (lane == 0) cand[r][w][round] = kl;
                if      (K0 == kl) K0 = 0ull;
                else if (K1 == kl) K1 = 0ull;
                else if (K2 == kl) K2 = 0ull;
                else if (K3 == kl) K3 = 0ull;
            }
            cnt = 8;
        }
        if (lane == 0) ccnt[r][w] = cnt;
    }
    __syncthreads();

    // ---- stage B: per-row exact top-8 of candidates + softmax + V gather ----
    const float* vtb = vt + (size_t)b * N_ * C_;
    #pragma unroll 1
    for (int rr = 0; rr < 4; ++rr) {
        const int r = w * 4 + rr;
        const int seg = lane >> 5;
        const int idx = lane & 31;
        unsigned long long k0 = (idx < ccnt[r][seg])     ? cand[r][seg][idx]     : 0ull;
        unsigned long long k1 = (idx < ccnt[r][seg + 2]) ? cand[r][seg + 2][idx] : 0ull;
        float4 o = make_float4(0.f, 0.f, 0.f, 0.f);
        float S = 0.f, vmax = 0.f;
        #pragma unroll 1
        for (int round = 0; round < 8; ++round) {
            unsigned long long km = k0 > k1 ? k0 : k1;
            #pragma unroll
            for (int off = 32; off >= 1; off >>= 1) {
                const unsigned long long ks = __shfl_xor(km, off);
                if (ks > km) km = ks;
            }
            const unsigned int mono = (unsigned int)(km >> 10);
            const unsigned int mm   = 1023u - ((unsigned int)km & 1023u);
            const unsigned int bits = (mono & 0x80000000u) ? (mono & 0x7FFFFFFFu) : ~mono;
            const float vraw = __uint_as_float(bits);
            if (round == 0) vmax = vraw;
            const float e = __expf((vraw - vmax) * 0.125f);
            S += e;
            const float4 vv = *(const float4*)&vtb[(size_t)mm * C_ + lane * 4];
            o.x += e * vv.x; o.y += e * vv.y; o.z += e * vv.z; o.w += e * vv.w;
            if (k0 == km) k0 = 0ull;
            if (k1 == km) k1 = 0ull;
        }
        const float inv = 1.f / S;
        *(float4*)&out_tile[r][lane * 4] = make_float4(o.x*inv, o.y*inv, o.z*inv, o.w*inv);
    }
    __syncthreads();

    // ---- residual + (b, c, n) write ----
    const float sc = scale[0];
    const float* xb = x + (size_t)b * C_ * N_;
    float* ob = out + (size_t)b * C_ * N_;
    #pragma unroll
    for (int i = 0; i < 16; ++i) {
        const int cc = i * 16 + (t >> 4);
        const int nl = t & 15;
        const size_t gi = (size_t)cc * N_ + n0 + nl;
        ob[gi] = xb[gi] + sc * out_tile[nl][cc];
    }
}

extern "C" void kernel_launch(void* const* d_in, const int* in_sizes, int n_in,
                              void* d_out, int out_size, void* d_ws, size_t ws_size,
                              hipStream_t stream) {
    const float* x     = (const float*)d_in[0];
    const float* wq    = (const float*)d_in[1];
    const float* bq    = (const float*)d_in[2];
    const float* wk    = (const float*)d_in[3];
    const float* bk    = (const float*)d_in[4];
    const float* wv    = (const float*)d_in[5];
    const float* bv    = (const float*)d_in[6];
    const float* scale = (const float*)d_in[7];
    float* out = (float*)d_out;

    float* qk = (float*)d_ws;                    // (b,128,n) fp32 = 16.8 MB
    float* vt = qk + (size_t)B_ * 128 * N_;      // (b,n,c)  fp32 = 33.6 MB

    proj_kernel<<<dim3(80, B_), 256, 0, stream>>>(x, wq, bq, wk, bk, wv, bv, qk, vt);
    attn_kernel<<<dim3(N_ / 16, B_), 256, 0, stream>>>(x, qk, vt, scale, out);
}

// Round 6
// 230.785 us; speedup vs baseline: 1.7614x; 1.1416x over previous
//
#include <hip/hip_runtime.h>

#define B_ 32
#define C_ 256
#define N_ 1024
#define D_ 64

// key = (monotone(v) << 10) | (1023 - m): larger key <=> larger v, tie -> smaller m.
__device__ __forceinline__ unsigned long long pack_key(float v, int m) {
    const unsigned int bits = __float_as_uint(v);
    const unsigned int mono = (bits & 0x80000000u) ? ~bits : (bits | 0x80000000u);
    return ((unsigned long long)mono << 10) | (unsigned long long)(1023 - m);
}

// ---------------------------------------------------------------------------
// Kernel 0: transpose W_all = [wq(64); wk(64); wv(256)] into wt[c][384].
// Bit-identical values, just relaid for wave-uniform (scalar) streaming.
// ---------------------------------------------------------------------------
__global__ __launch_bounds__(384) void wt_kernel(
    const float* __restrict__ wq, const float* __restrict__ wk,
    const float* __restrict__ wv, float* __restrict__ wt)
{
    const int c = blockIdx.x;          // 0..255
    const int r = threadIdx.x;         // 0..383
    float v;
    if      (r < 64)  v = wq[(size_t)r * C_ + c];
    else if (r < 128) v = wk[(size_t)(r - 64) * C_ + c];
    else              v = wv[(size_t)(r - 128) * C_ + c];
    wt[(size_t)c * 384 + r] = v;
}

// ---------------------------------------------------------------------------
// Kernel 1: all projections, LDS-free, W-stationary streaming.
// Block = 256 thr = 4 waves; wave owns 8 output rows (uniform -> s_load W);
// lane owns 4 consecutive n. Per c: 2 uniform float4 W loads + 1 coalesced
// float4 x load + 32 fmaf (ascending-c chain per (r,n) -> bit-exact emulation
// of the np einsum; one rounded bias add at the end).
// Grid (12 row-groups of 32, 4 n-tiles of 256, B).
//   rows 0..127  -> qk[(b*128+r)*N + n]
//   rows 128..383 -> vt[(b*N+n)*C + (r-128)]
// ---------------------------------------------------------------------------
__global__ __launch_bounds__(256) void proj_kernel(
    const float* __restrict__ x, const float* __restrict__ wt,
    const float* __restrict__ bq, const float* __restrict__ bk,
    const float* __restrict__ bv,
    float* __restrict__ qk, float* __restrict__ vt)
{
    const int rg = blockIdx.x;         // 0..11
    const int nt = blockIdx.y;         // 0..3
    const int b  = blockIdx.z;
    const int r0 = rg * 32;
    const int n0 = nt * 256;
    const int lane = threadIdx.x & 63;
    const int wu = __builtin_amdgcn_readfirstlane(threadIdx.x >> 6);
    const int rw = r0 + wu * 8;        // this wave's first row (uniform)

    float acc[8][4];
    #pragma unroll
    for (int i = 0; i < 8; ++i)
        #pragma unroll
        for (int j = 0; j < 4; ++j) acc[i][j] = 0.f;

    const float* xp = x + (size_t)b * C_ * N_ + n0 + lane * 4;
    const float* wp = wt + rw;

    #pragma unroll 4
    for (int c = 0; c < C_; ++c) {
        const float4 xv = *(const float4*)(xp + (size_t)c * N_);
        const float* wr = wp + (size_t)c * 384;
        const float4 w0 = *(const float4*)(wr);        // uniform -> s_load
        const float4 w1 = *(const float4*)(wr + 4);    // uniform -> s_load
        const float wv8[8] = { w0.x, w0.y, w0.z, w0.w, w1.x, w1.y, w1.z, w1.w };
        #pragma unroll
        for (int i = 0; i < 8; ++i) {
            acc[i][0] = fmaf(wv8[i], xv.x, acc[i][0]);
            acc[i][1] = fmaf(wv8[i], xv.y, acc[i][1]);
            acc[i][2] = fmaf(wv8[i], xv.z, acc[i][2]);
            acc[i][3] = fmaf(wv8[i], xv.w, acc[i][3]);
        }
    }

    if (r0 < 128) {
        #pragma unroll
        for (int i = 0; i < 8; ++i) {
            const int R = rw + i;
            const float bb = (R < 64) ? bq[R] : bk[R - 64];
            float4 o; o.x = acc[i][0]+bb; o.y = acc[i][1]+bb; o.z = acc[i][2]+bb; o.w = acc[i][3]+bb;
            *(float4*)&qk[((size_t)b * 128 + R) * N_ + n0 + lane * 4] = o;
        }
    } else {
        const int e0 = rw - 128;
        float be[8];
        #pragma unroll
        for (int i = 0; i < 8; ++i) be[i] = bv[e0 + i];
        #pragma unroll
        for (int j = 0; j < 4; ++j) {
            const int n = n0 + lane * 4 + j;
            float* dst = &vt[((size_t)b * N_ + n) * C_ + e0];
            float4 o0; o0.x = acc[0][j]+be[0]; o0.y = acc[1][j]+be[1]; o0.z = acc[2][j]+be[2]; o0.w = acc[3][j]+be[3];
            float4 o1; o1.x = acc[4][j]+be[4]; o1.y = acc[5][j]+be[5]; o1.z = acc[6][j]+be[6]; o1.w = acc[7][j]+be[7];
            *(float4*)dst       = o0;
            *(float4*)(dst + 4) = o1;
        }
    }
}

// ---------------------------------------------------------------------------
// Kernel 2: fp32 sim (bit-exact ascending-d fmaf chain on raw values; /8 is
// exact, applied only inside exp) + threshold-filtered exact top-8 + softmax
// + fp32 V gather + residual.
// Block = 16 rows x 8 waves (512 thr); wave w owns m-slice [128w, 128w+128),
// 2 m/lane -> 32 accumulators/lane (low VGPR -> 7 waves/SIMD).
// Output tile is written INTO the cand buffer (union) to keep LDS at 38.9 KB
// -> 4 blocks/CU = 32 waves/CU ceiling.
// ---------------------------------------------------------------------------
__global__ __launch_bounds__(512) void attn_kernel(
    const float* __restrict__ x,
    const float* __restrict__ qk,
    const float* __restrict__ vt,
    const float* __restrict__ scale,
    float* __restrict__ out)
{
    const int b  = blockIdx.y;
    const int n0 = blockIdx.x * 16;
    const int t  = threadIdx.x;
    const int lane = t & 63;
    const int w  = t >> 6;

    // cand row stride 266 u64 = 2128 B: 16B-aligned rows; reused as the
    // 256-float output row after stage B (offsets 0..1023 < 2128).
    __shared__ unsigned long long cand[16][266];   // 34048 B
    __shared__ int   ccnt[16][8];                  //   512 B
    __shared__ __align__(16) float q_lds[16][68];  //  4352 B

    for (int idx = t; idx < 1024; idx += 512) {
        const int r = idx & 15, d = idx >> 4;
        q_lds[r][d] = qk[((size_t)b * 128 + d) * N_ + n0 + r];
    }
    __syncthreads();

    const int m_base = w * 128 + lane * 2;

    float a0[16], a1[16];
    #pragma unroll
    for (int r = 0; r < 16; ++r) { a0[r] = 0.f; a1[r] = 0.f; }

    const float* kb = qk + ((size_t)b * 128 + 64) * N_ + m_base;
    #pragma unroll 2
    for (int d0 = 0; d0 < D_; d0 += 4) {
        const float2 kv0 = *(const float2*)&kb[(size_t)(d0+0) * N_];
        const float2 kv1 = *(const float2*)&kb[(size_t)(d0+1) * N_];
        const float2 kv2 = *(const float2*)&kb[(size_t)(d0+2) * N_];
        const float2 kv3 = *(const float2*)&kb[(size_t)(d0+3) * N_];
        #pragma unroll
        for (int r = 0; r < 16; ++r) {
            const float4 qf = *(const float4*)&q_lds[r][d0];
            a0[r] = fmaf(qf.x, kv0.x, a0[r]); a0[r] = fmaf(qf.y, kv1.x, a0[r]);
            a0[r] = fmaf(qf.z, kv2.x, a0[r]); a0[r] = fmaf(qf.w, kv3.x, a0[r]);
            a1[r] = fmaf(qf.x, kv0.y, a1[r]); a1[r] = fmaf(qf.y, kv1.y, a1[r]);
            a1[r] = fmaf(qf.z, kv2.y, a1[r]); a1[r] = fmaf(qf.w, kv3.y, a1[r]);
        }
    }

    // ---- stage A: per-slice threshold filter + compaction (exact superset) ----
    const unsigned long long lt = (1ull << lane) - 1ull;
    #pragma unroll
    for (int r = 0; r < 16; ++r) {
        const int nrow = n0 + r;
        float t0 = a0[r], t1 = a1[r];
        const int dj = nrow - m_base;
        if      (dj == 0) t0 = -1.0e9f;
        else if (dj == 1) t1 = -1.0e9f;

        float lm = fmaxf(t0, t1);
        lm = fmaxf(lm, __shfl_xor(lm, 1));
        lm = fmaxf(lm, __shfl_xor(lm, 2));
        lm = fmaxf(lm, __shfl_xor(lm, 4));      // max over group of 8 lanes (16 m)
        float Th = lm;
        Th = fminf(Th, __shfl_xor(Th, 8));
        Th = fminf(Th, __shfl_xor(Th, 16));
        Th = fminf(Th, __shfl_xor(Th, 32));     // min of 8 group maxes <= slice V8

        int cnt = 0;
        {
            const bool p = (t0 >= Th);
            const unsigned long long msk = __ballot(p);
            const int pos = cnt + (int)__popcll(msk & lt);
            if (p && pos < 32) cand[r][w * 33 + pos] = pack_key(t0, m_base + 0);
            cnt += (int)__popcll(msk);
        }
        {
            const bool p = (t1 >= Th);
            const unsigned long long msk = __ballot(p);
            const int pos = cnt + (int)__popcll(msk & lt);
            if (p && pos < 32) cand[r][w * 33 + pos] = pack_key(t1, m_base + 1);
            cnt += (int)__popcll(msk);
        }

        if (cnt > 32) {   // exact fallback: slice top-8 via 8 extraction rounds
            unsigned long long K0 = pack_key(t0, m_base + 0);
            unsigned long long K1 = pack_key(t1, m_base + 1);
            #pragma unroll 1
            for (int round = 0; round < 8; ++round) {
                unsigned long long kl = K0 > K1 ? K0 : K1;
                #pragma unroll
                for (int off = 32; off >= 1; off >>= 1) {
                    const unsigned long long ks = __shfl_xor(kl, off);
                    if (ks > kl) kl = ks;
                }
                if (lane == 0) cand[r][w * 33 + round] = kl;
                if      (K0 == kl) K0 = 0ull;
                else if (K1 == kl) K1 = 0ull;
            }
            cnt = 8;
        }
        if (lane == 0) ccnt[r][w] = cnt;
    }
    __syncthreads();

    // ---- stage B: per-row exact top-8 over 8 slices + softmax + V gather ----
    const float* vtb = vt + (size_t)b * N_ * C_;
    #pragma unroll 1
    for (int rr = 0; rr < 2; ++rr) {
        const int r = w * 2 + rr;
        const int seg = lane >> 3;      // 0..7
        const int i0  = lane & 7;       // 0..7
        const int cn  = ccnt[r][seg];
        unsigned long long k0 = (i0      < cn) ? cand[r][seg * 33 + i0     ] : 0ull;
        unsigned long long k1 = (i0 + 8  < cn) ? cand[r][seg * 33 + i0 + 8 ] : 0ull;
        unsigned long long k2 = (i0 + 16 < cn) ? cand[r][seg * 33 + i0 + 16] : 0ull;
        unsigned long long k3 = (i0 + 24 < cn) ? cand[r][seg * 33 + i0 + 24] : 0ull;
        float4 o = make_float4(0.f, 0.f, 0.f, 0.f);
        float S = 0.f, vmax = 0.f;
        #pragma unroll 1
        for (int round = 0; round < 8; ++round) {
            unsigned long long km = k0 > k1 ? k0 : k1;
            km = k2 > km ? k2 : km;
            km = k3 > km ? k3 : km;
            #pragma unroll
            for (int off = 32; off >= 1; off >>= 1) {
                const unsigned long long ks = __shfl_xor(km, off);
                if (ks > km) km = ks;
            }
            const unsigned int mono = (unsigned int)(km >> 10);
            const unsigned int mm   = 1023u - ((unsigned int)km & 1023u);
            const unsigned int bits = (mono & 0x80000000u) ? (mono & 0x7FFFFFFFu) : ~mono;
            const float vraw = __uint_as_float(bits);
            if (round == 0) vmax = vraw;
            const float e = __expf((vraw - vmax) * 0.125f);
            S += e;
            const float4 vv = *(const float4*)&vtb[(size_t)mm * C_ + lane * 4];
            o.x += e * vv.x; o.y += e * vv.y; o.z += e * vv.z; o.w += e * vv.w;
            if (k0 == km) k0 = 0ull;
            if (k1 == km) k1 = 0ull;
            if (k2 == km) k2 = 0ull;
            if (k3 == km) k3 = 0ull;
        }
        const float inv = 1.f / S;
        float* orow = (float*)&cand[r][0];   // union: out row over cand row r
        *(float4*)&orow[lane * 4] = make_float4(o.x*inv, o.y*inv, o.z*inv, o.w*inv);
    }
    __syncthreads();

    // ---- residual + (b, c, n) write ----
    const float sc = scale[0];
    const float* xb = x + (size_t)b * C_ * N_;
    float* ob = out + (size_t)b * C_ * N_;
    const int nl = t & 15;
    const int cg = t >> 4;               // 0..31
    const float* orow = (const float*)&cand[nl][0];
    #pragma unroll
    for (int i = 0; i < 8; ++i) {
        const int cc = i * 32 + cg;
        const size_t gi = (size_t)cc * N_ + n0 + nl;
        ob[gi] = xb[gi] + sc * orow[cc];
    }
}

extern "C" void kernel_launch(void* const* d_in, const int* in_sizes, int n_in,
                              void* d_out, int out_size, void* d_ws, size_t ws_size,
                              hipStream_t stream) {
    const float* x     = (const float*)d_in[0];
    const float* wq    = (const float*)d_in[1];
    const float* bq    = (const float*)d_in[2];
    const float* wk    = (const float*)d_in[3];
    const float* bk    = (const float*)d_in[4];
    const float* wv    = (const float*)d_in[5];
    const float* bv    = (const float*)d_in[6];
    const float* scale = (const float*)d_in[7];
    float* out = (float*)d_out;

    float* qk = (float*)d_ws;                    // (b,128,n) fp32 = 16.8 MB
    float* vt = qk + (size_t)B_ * 128 * N_;      // (b,n,c)  fp32 = 33.6 MB
    float* wt = vt + (size_t)B_ * N_ * C_;       // (c,384)  fp32 =  0.4 MB

    wt_kernel<<<dim3(256), 384, 0, stream>>>(wq, wk, wv, wt);
    proj_kernel<<<dim3(12, 4, B_), 256, 0, stream>>>(x, wt, bq, bk, bv, qk, vt);
    attn_kernel<<<dim3(N_ / 16, B_), 512, 0, stream>>>(x, qk, vt, scale, out);
}

// Round 7
// 218.085 us; speedup vs baseline: 1.8640x; 1.0582x over previous
//
#include <hip/hip_runtime.h>

#define B_ 32
#define C_ 256
#define N_ 1024
#define D_ 64

// key = (monotone(v) << 10) | (1023 - m): larger key <=> larger v, tie -> smaller m.
__device__ __forceinline__ unsigned long long pack_key(float v, int m) {
    const unsigned int bits = __float_as_uint(v);
    const unsigned int mono = (bits & 0x80000000u) ? ~bits : (bits | 0x80000000u);
    return ((unsigned long long)mono << 10) | (unsigned long long)(1023 - m);
}

// ---------------------------------------------------------------------------
// Kernel 0: transpose W_all = [wq(64); wk(64); wv(256)] into wt[c][384].
// ---------------------------------------------------------------------------
__global__ __launch_bounds__(384) void wt_kernel(
    const float* __restrict__ wq, const float* __restrict__ wk,
    const float* __restrict__ wv, float* __restrict__ wt)
{
    const int c = blockIdx.x;          // 0..255
    const int r = threadIdx.x;         // 0..383
    float v;
    if      (r < 64)  v = wq[(size_t)r * C_ + c];
    else if (r < 128) v = wk[(size_t)(r - 64) * C_ + c];
    else              v = wv[(size_t)(r - 128) * C_ + c];
    wt[(size_t)c * 384 + r] = v;
}

// ---------------------------------------------------------------------------
// Kernel 1: all projections, LDS-free, W-stationary streaming.
// Wave owns 8 output rows (uniform -> s_load W); lane owns 4 consecutive n.
// Ascending-c fmaf chain per (r,n) -> bit-exact np.einsum emulation.
// ---------------------------------------------------------------------------
__global__ __launch_bounds__(256) void proj_kernel(
    const float* __restrict__ x, const float* __restrict__ wt,
    const float* __restrict__ bq, const float* __restrict__ bk,
    const float* __restrict__ bv,
    float* __restrict__ qk, float* __restrict__ vt)
{
    const int rg = blockIdx.x;         // 0..11
    const int nt = blockIdx.y;         // 0..3
    const int b  = blockIdx.z;
    const int r0 = rg * 32;
    const int n0 = nt * 256;
    const int lane = threadIdx.x & 63;
    const int wu = __builtin_amdgcn_readfirstlane(threadIdx.x >> 6);
    const int rw = r0 + wu * 8;        // this wave's first row (uniform)

    float acc[8][4];
    #pragma unroll
    for (int i = 0; i < 8; ++i)
        #pragma unroll
        for (int j = 0; j < 4; ++j) acc[i][j] = 0.f;

    const float* xp = x + (size_t)b * C_ * N_ + n0 + lane * 4;
    const float* wp = wt + rw;

    #pragma unroll 8
    for (int c = 0; c < C_; ++c) {
        const float4 xv = *(const float4*)(xp + (size_t)c * N_);
        const float* wr = wp + (size_t)c * 384;
        const float4 w0 = *(const float4*)(wr);        // uniform -> s_load
        const float4 w1 = *(const float4*)(wr + 4);    // uniform -> s_load
        const float wv8[8] = { w0.x, w0.y, w0.z, w0.w, w1.x, w1.y, w1.z, w1.w };
        #pragma unroll
        for (int i = 0; i < 8; ++i) {
            acc[i][0] = fmaf(wv8[i], xv.x, acc[i][0]);
            acc[i][1] = fmaf(wv8[i], xv.y, acc[i][1]);
            acc[i][2] = fmaf(wv8[i], xv.z, acc[i][2]);
            acc[i][3] = fmaf(wv8[i], xv.w, acc[i][3]);
        }
    }

    if (r0 < 128) {
        #pragma unroll
        for (int i = 0; i < 8; ++i) {
            const int R = rw + i;
            const float bb = (R < 64) ? bq[R] : bk[R - 64];
            float4 o; o.x = acc[i][0]+bb; o.y = acc[i][1]+bb; o.z = acc[i][2]+bb; o.w = acc[i][3]+bb;
            *(float4*)&qk[((size_t)b * 128 + R) * N_ + n0 + lane * 4] = o;
        }
    } else {
        const int e0 = rw - 128;
        float be[8];
        #pragma unroll
        for (int i = 0; i < 8; ++i) be[i] = bv[e0 + i];
        #pragma unroll
        for (int j = 0; j < 4; ++j) {
            const int n = n0 + lane * 4 + j;
            float* dst = &vt[((size_t)b * N_ + n) * C_ + e0];
            float4 o0; o0.x = acc[0][j]+be[0]; o0.y = acc[1][j]+be[1]; o0.z = acc[2][j]+be[2]; o0.w = acc[3][j]+be[3];
            float4 o1; o1.x = acc[4][j]+be[4]; o1.y = acc[5][j]+be[5]; o1.z = acc[6][j]+be[6]; o1.w = acc[7][j]+be[7];
            *(float4*)dst       = o0;
            *(float4*)(dst + 4) = o1;
        }
    }
}

// ---------------------------------------------------------------------------
// Kernel 2: fp32 sim (bit-exact ascending-d fmaf chain; /8 exact, applied
// inside exp only) + threshold-filtered exact top-8 + softmax + V gather +
// residual.  Block = 16 rows x 8 waves (512 thr); wave w owns m-slice
// [128w, 128w+128), 2 m/lane.
// q is WAVE-UNIFORM -> read via scalar loads (SGPR), no LDS staging.
// ---------------------------------------------------------------------------
__global__ __launch_bounds__(512) void attn_kernel(
    const float* __restrict__ x,
    const float* __restrict__ qk,
    const float* __restrict__ vt,
    const float* __restrict__ scale,
    float* __restrict__ out)
{
    const int b  = blockIdx.y;
    const int n0 = blockIdx.x * 16;
    const int t  = threadIdx.x;
    const int lane = t & 63;
    const int w  = t >> 6;

    // cand row stride 266 u64 = 2128 B (16B-aligned rows); reused as the
    // 256-float output row after stage B.
    __shared__ unsigned long long cand[16][266];   // 34048 B
    __shared__ int   ccnt[16][8];                  //   512 B

    const int m_base = w * 128 + lane * 2;

    float a0[16], a1[16];
    #pragma unroll
    for (int r = 0; r < 16; ++r) { a0[r] = 0.f; a1[r] = 0.f; }

    const float* kb = qk + ((size_t)b * 128 + 64) * N_ + m_base;
    const float* qb = qk + (size_t)b * 128 * N_ + n0;   // uniform base

    #pragma unroll 2
    for (int d0 = 0; d0 < D_; d0 += 4) {
        const float2 kv0 = *(const float2*)&kb[(size_t)(d0+0) * N_];
        const float2 kv1 = *(const float2*)&kb[(size_t)(d0+1) * N_];
        const float2 kv2 = *(const float2*)&kb[(size_t)(d0+2) * N_];
        const float2 kv3 = *(const float2*)&kb[(size_t)(d0+3) * N_];

        // wave-uniform q: 4 d x 16 rows -> s_load_dwordx4 (rows are contiguous)
        float qs[4][16];
        #pragma unroll
        for (int dd = 0; dd < 4; ++dd) {
            #pragma unroll
            for (int rq = 0; rq < 4; ++rq) {
                const float4 qv = *(const float4*)&qb[(size_t)(d0 + dd) * N_ + rq * 4];
                qs[dd][rq*4+0] = qv.x; qs[dd][rq*4+1] = qv.y;
                qs[dd][rq*4+2] = qv.z; qs[dd][rq*4+3] = qv.w;
            }
        }

        #pragma unroll
        for (int r = 0; r < 16; ++r) {
            a0[r] = fmaf(qs[0][r], kv0.x, a0[r]); a0[r] = fmaf(qs[1][r], kv1.x, a0[r]);
            a0[r] = fmaf(qs[2][r], kv2.x, a0[r]); a0[r] = fmaf(qs[3][r], kv3.x, a0[r]);
            a1[r] = fmaf(qs[0][r], kv0.y, a1[r]); a1[r] = fmaf(qs[1][r], kv1.y, a1[r]);
            a1[r] = fmaf(qs[2][r], kv2.y, a1[r]); a1[r] = fmaf(qs[3][r], kv3.y, a1[r]);
        }
    }

    // ---- stage A: per-slice threshold filter + compaction (exact superset) ----
    const unsigned long long lt = (1ull << lane) - 1ull;
    #pragma unroll
    for (int r = 0; r < 16; ++r) {
        const int nrow = n0 + r;
        float t0 = a0[r], t1 = a1[r];
        const int dj = nrow - m_base;
        if      (dj == 0) t0 = -1.0e9f;
        else if (dj == 1) t1 = -1.0e9f;

        float lm = fmaxf(t0, t1);
        lm = fmaxf(lm, __shfl_xor(lm, 1));
        lm = fmaxf(lm, __shfl_xor(lm, 2));
        lm = fmaxf(lm, __shfl_xor(lm, 4));      // max over group of 8 lanes (16 m)
        float Th = lm;
        Th = fminf(Th, __shfl_xor(Th, 8));
        Th = fminf(Th, __shfl_xor(Th, 16));
        Th = fminf(Th, __shfl_xor(Th, 32));     // min of 8 group maxes <= slice V8

        int cnt = 0;
        {
            const bool p = (t0 >= Th);
            const unsigned long long msk = __ballot(p);
            const int pos = cnt + (int)__popcll(msk & lt);
            if (p && pos < 32) cand[r][w * 33 + pos] = pack_key(t0, m_base + 0);
            cnt += (int)__popcll(msk);
        }
        {
            const bool p = (t1 >= Th);
            const unsigned long long msk = __ballot(p);
            const int pos = cnt + (int)__popcll(msk & lt);
            if (p && pos < 32) cand[r][w * 33 + pos] = pack_key(t1, m_base + 1);
            cnt += (int)__popcll(msk);
        }

        if (cnt > 32) {   // exact fallback: slice top-8 via 8 extraction rounds
            unsigned long long K0 = pack_key(t0, m_base + 0);
            unsigned long long K1 = pack_key(t1, m_base + 1);
            #pragma unroll 1
            for (int round = 0; round < 8; ++round) {
                unsigned long long kl = K0 > K1 ? K0 : K1;
                #pragma unroll
                for (int off = 32; off >= 1; off >>= 1) {
                    const unsigned long long ks = __shfl_xor(kl, off);
                    if (ks > kl) kl = ks;
                }
                if (lane == 0) cand[r][w * 33 + round] = kl;
                if      (K0 == kl) K0 = 0ull;
                else if (K1 == kl) K1 = 0ull;
            }
            cnt = 8;
        }
        if (lane == 0) ccnt[r][w] = cnt;
    }
    __syncthreads();

    // ---- stage B: per-row exact top-8 over 8 slices + softmax + V gather ----
    const float* vtb = vt + (size_t)b * N_ * C_;
    #pragma unroll 1
    for (int rr = 0; rr < 2; ++rr) {
        const int r = w * 2 + rr;
        const int seg = lane >> 3;      // 0..7
        const int i0  = lane & 7;       // 0..7
        const int cn  = ccnt[r][seg];
        unsigned long long k0 = (i0      < cn) ? cand[r][seg * 33 + i0     ] : 0ull;
        unsigned long long k1 = (i0 + 8  < cn) ? cand[r][seg * 33 + i0 + 8 ] : 0ull;
        unsigned long long k2 = (i0 + 16 < cn) ? cand[r][seg * 33 + i0 + 16] : 0ull;
        unsigned long long k3 = (i0 + 24 < cn) ? cand[r][seg * 33 + i0 + 24] : 0ull;

        float ev[8]; unsigned int mi[8];
        float S = 0.f, vmax = 0.f;
        #pragma unroll
        for (int round = 0; round < 8; ++round) {
            unsigned long long km = k0 > k1 ? k0 : k1;
            km = k2 > km ? k2 : km;
            km = k3 > km ? k3 : km;
            #pragma unroll
            for (int off = 32; off >= 1; off >>= 1) {
                const unsigned long long ks = __shfl_xor(km, off);
                if (ks > km) km = ks;
            }
            const unsigned int mono = (unsigned int)(km >> 10);
            mi[round] = 1023u - ((unsigned int)km & 1023u);
            const unsigned int bits = (mono & 0x80000000u) ? (mono & 0x7FFFFFFFu) : ~mono;
            const float vraw = __uint_as_float(bits);
            if (round == 0) vmax = vraw;
            const float e = __expf((vraw - vmax) * 0.125f);
            S += e;
            ev[round] = e;
            if (k0 == km) k0 = 0ull;
            if (k1 == km) k1 = 0ull;
            if (k2 == km) k2 = 0ull;
            if (k3 == km) k3 = 0ull;
        }

        // batched gathers: 8 independent L2 loads in flight
        float4 o = make_float4(0.f, 0.f, 0.f, 0.f);
        #pragma unroll
        for (int round = 0; round < 8; ++round) {
            const float4 vv = *(const float4*)&vtb[(size_t)mi[round] * C_ + lane * 4];
            o.x += ev[round] * vv.x; o.y += ev[round] * vv.y;
            o.z += ev[round] * vv.z; o.w += ev[round] * vv.w;
        }
        const float inv = 1.f / S;
        float* orow = (float*)&cand[r][0];   // union: out row over cand row r
        *(float4*)&orow[lane * 4] = make_float4(o.x*inv, o.y*inv, o.z*inv, o.w*inv);
    }
    __syncthreads();

    // ---- residual + (b, c, n) write ----
    const float sc = scale[0];
    const float* xb = x + (size_t)b * C_ * N_;
    float* ob = out + (size_t)b * C_ * N_;
    const int nl = t & 15;
    const int cg = t >> 4;               // 0..31
    const float* orow = (const float*)&cand[nl][0];
    #pragma unroll
    for (int i = 0; i < 8; ++i) {
        const int cc = i * 32 + cg;
        const size_t gi = (size_t)cc * N_ + n0 + nl;
        ob[gi] = xb[gi] + sc * orow[cc];
    }
}

extern "C" void kernel_launch(void* const* d_in, const int* in_sizes, int n_in,
                              void* d_out, int out_size, void* d_ws, size_t ws_size,
                              hipStream_t stream) {
    const float* x     = (const float*)d_in[0];
    const float* wq    = (const float*)d_in[1];
    const float* bq    = (const float*)d_in[2];
    const float* wk    = (const float*)d_in[3];
    const float* bk    = (const float*)d_in[4];
    const float* wv    = (const float*)d_in[5];
    const float* bv    = (const float*)d_in[6];
    const float* scale = (const float*)d_in[7];
    float* out = (float*)d_out;

    float* qk = (float*)d_ws;                    // (b,128,n) fp32 = 16.8 MB
    float* vt = qk + (size_t)B_ * 128 * N_;      // (b,n,c)  fp32 = 33.6 MB
    float* wt = vt + (size_t)B_ * N_ * C_;       // (c,384)  fp32 =  0.4 MB

    wt_kernel<<<dim3(256), 384, 0, stream>>>(wq, wk, wv, wt);
    proj_kernel<<<dim3(12, 4, B_), 256, 0, stream>>>(x, wt, bq, bk, bv, qk, vt);
    attn_kernel<<<dim3(N_ / 16, B_), 512, 0, stream>>>(x, qk, vt, scale, out);
}